// Round 18
// baseline (89.292 us; speedup 1.0000x reference)
//
#include <hip/hip_runtime.h>
#include <math.h>

typedef __attribute__((ext_vector_type(4))) float f32x4;
typedef __attribute__((ext_vector_type(8))) short short8;
typedef __attribute__((ext_vector_type(4))) short s16x4;
typedef __attribute__((ext_vector_type(8))) __bf16 bf16x8;
typedef __attribute__((ext_vector_type(2))) __bf16 bf16x2;
typedef __attribute__((ext_vector_type(2))) unsigned uint32x2;

#define NB 4
#define NS 2048
#define NHID 576
#define NHEADS 9
#define NKVH 3
#define NHD 64
#define NM (NB * NS)      // 8192 rows
#define NQKV 960          // logical qkv cols
#define QKS 768           // stored qkv row stride (q+k only; v goes to vt)
#define NGRP 3            // NHEADS / NKVH
#define QSC 0.18033688f   // (1/sqrt(64)) * log2(e)

static __device__ __forceinline__ unsigned short f2bf(float f) {
  union { float f; unsigned u; } v; v.f = f;
  unsigned r = v.u + 0x7FFFu + ((v.u >> 16) & 1u);
  return (unsigned short)(r >> 16);
}
static __device__ __forceinline__ unsigned pk2bf(float a, float b) {
  bf16x2 h;
  h.x = (__bf16)a;
  h.y = (__bf16)b;
  return __builtin_bit_cast(unsigned, h);
}
static __device__ __forceinline__ float bf2f(unsigned short h) {
  union { unsigned u; float f; } v; v.u = ((unsigned)h) << 16;
  return v.f;
}
static __device__ __forceinline__ float fexp2(float x) {
  return __builtin_amdgcn_exp2f(x);   // bare v_exp_f32 (no OCML range handling)
}
static __device__ __forceinline__ f32x4 mfma16(short8 a, short8 b, f32x4 c) {
  return __builtin_amdgcn_mfma_f32_16x16x32_bf16(
      __builtin_bit_cast(bf16x8, a), __builtin_bit_cast(bf16x8, b), c, 0, 0, 0);
}
static __device__ __forceinline__ f32x4 mfma16k16(s16x4 a, s16x4 b, f32x4 c) {
#if defined(__HIP_DEVICE_COMPILE__)
#if __has_builtin(__builtin_amdgcn_mfma_f32_16x16x16bf16_1k)
  return __builtin_amdgcn_mfma_f32_16x16x16bf16_1k(a, b, c, 0, 0, 0);
#else
  asm volatile("v_mfma_f32_16x16x16_bf16 %0, %1, %2, %0"
               : "+v"(c) : "v"(a), "v"(b));
  return c;
#endif
#else
  return c;   // host pass never executes device code
#endif
}
static __device__ __forceinline__ void gload16(const void* g, void* l) {
  __builtin_amdgcn_global_load_lds(
      (const __attribute__((address_space(1))) void*)g,
      (__attribute__((address_space(3))) void*)l, 16, 0, 0);
}

// ---------------- fused prep: x f32->bf16 (blocks 0..2303) + 4 weight transposes ----------------
__global__ __launch_bounds__(256)
void k_prep(const float* __restrict__ x, unsigned short* __restrict__ xb,
            const float* __restrict__ Wq, const float* __restrict__ Wk,
            const float* __restrict__ Wv, const float* __restrict__ Wo,
            unsigned short* __restrict__ wqkvT, unsigned short* __restrict__ woT) {
  __shared__ unsigned short tile[64 * 72];
  int bid = blockIdx.x;
  if (bid < 2304) {
    const int t = bid * 256 + threadIdx.x;   // t < NM*NHID/8 exactly
    const f32x4* sp = (const f32x4*)(x + (size_t)t * 8);
    f32x4 a = sp[0], b = sp[1];
    union { short8 v; unsigned short u[8]; } o;
#pragma unroll
    for (int e = 0; e < 4; ++e) { o.u[e] = f2bf(a[e]); o.u[4 + e] = f2bf(b[e]); }
    *(short8*)(xb + (size_t)t * 8) = o.v;
    return;
  }
  bid -= 2304;
  const float* src;
  unsigned short* dst;
  int C, bx, by;
  if (bid < 81) { src = Wq; dst = wqkvT; C = 576; bx = bid % 9; by = bid / 9; }
  else if (bid < 108) { int b2 = bid - 81; src = Wk; dst = wqkvT + 576 * 576; C = 192; bx = b2 % 3; by = b2 / 3; }
  else if (bid < 135) { int b2 = bid - 108; src = Wv; dst = wqkvT + 768 * 576; C = 192; bx = b2 % 3; by = b2 / 3; }
  else { int b2 = bid - 135; src = Wo; dst = woT; C = 576; bx = b2 % 9; by = b2 / 9; }
  const int R = 576;
  const int t = threadIdx.x;
  const int r0 = by * 64, c0 = bx * 64;
  {
    const int rl = t >> 2, cb = (t & 3) * 16;
    const float* sp = src + (size_t)(r0 + rl) * C + c0 + cb;
#pragma unroll
    for (int jj = 0; jj < 4; ++jj) {
      f32x4 v = *(const f32x4*)(sp + jj * 4);
#pragma unroll
      for (int e = 0; e < 4; ++e) tile[rl * 72 + cb + jj * 4 + e] = f2bf(v[e]);
    }
  }
  __syncthreads();
  {
    const int cl = t >> 2, rb = (t & 3) * 16;
    union { short8 v; unsigned short u[8]; } o0, o1;
#pragma unroll
    for (int jj = 0; jj < 8; ++jj) {
      o0.u[jj] = tile[(rb + jj) * 72 + cl];
      o1.u[jj] = tile[(rb + 8 + jj) * 72 + cl];
    }
    unsigned short* dp = dst + (size_t)(c0 + cl) * R + r0 + rb;
    *(short8*)dp = o0.v;
    *(short8*)(dp + 8) = o1.v;
  }
}

// ---------------- GEMM: C[M][N] = A[M][K](bf16) * Bt[N][K](bf16)^T ----------------
// BM=128 BN=128 BK=64, 4 waves (2x2 of 64x64), LDS dbuf, counted-vmcnt schedule.
// MODE 0 (QKV): cols <768 -> fused RoPE (+QSC on q), write qkv (stride 768);
//               cols 768..959 (V) -> write V^T to vt[(b*3+kh)][d][s] directly.
// MODE 1: f32 out plain (O-proj).
template <int MODE>
__global__ __launch_bounds__(256)
void k_gemm_bt(const unsigned short* __restrict__ A,
               const unsigned short* __restrict__ Bt,
               void* __restrict__ Cv,
               unsigned short* __restrict__ vtb,
               const float* __restrict__ cosT,
               const float* __restrict__ sinT,
               const int M, const int N, const int K) {
  __shared__ unsigned short a_lds[2][128 * 64];
  __shared__ unsigned short b_lds[2][128 * 64];
  const int tid = threadIdx.x;
  const int w = tid >> 6, l = tid & 63, g = l >> 4, c = l & 15;
  const int tm = blockIdx.y * 128, tn = blockIdx.x * 128;
  const int wm = w >> 1, wn = w & 1;
  f32x4 acc[4][4] = {};
  const int nk = K >> 6;

#define GSTAGE(k0, half)                                                   \
  {                                                                        \
    _Pragma("unroll")                                                      \
    for (int q = 0; q < 4; ++q) {                                          \
      const int o = q * 4096 + w * 1024 + l * 16;                          \
      const int row = o >> 7;                                              \
      const int wb = (o & 127) ^ ((row & 7) << 4);                         \
      gload16(A + (size_t)(tm + row) * K + (k0) + (wb >> 1),               \
              (void*)(a_lds[half] + ((q * 4096 + w * 1024) >> 1)));        \
      gload16(Bt + (size_t)(tn + row) * K + (k0) + (wb >> 1),              \
              (void*)(b_lds[half] + ((q * 4096 + w * 1024) >> 1)));        \
    }                                                                      \
  }

  GSTAGE(0, 0);

  for (int k = 0; k < nk; ++k) {
    if (k + 1 < nk) {
      GSTAGE((k + 1) << 6, (k + 1) & 1);
      asm volatile("s_waitcnt vmcnt(8)" ::: "memory");
    } else {
      asm volatile("s_waitcnt vmcnt(0)" ::: "memory");
    }
    __builtin_amdgcn_s_barrier();
    __builtin_amdgcn_sched_barrier(0);
    const char* al = (const char*)a_lds[k & 1];
    const char* bl = (const char*)b_lds[k & 1];
#pragma unroll
    for (int dc = 0; dc < 2; ++dc) {
      short8 af[4], bf[4];
#pragma unroll
      for (int mt = 0; mt < 4; ++mt) {
        const int row = wm * 64 + mt * 16 + c;
        const int byt = ((row << 7) + (dc << 6) + (g << 4)) ^ ((row & 7) << 4);
        af[mt] = *(const short8*)(al + byt);
      }
#pragma unroll
      for (int nt = 0; nt < 4; ++nt) {
        const int row = wn * 64 + nt * 16 + c;
        const int byt = ((row << 7) + (dc << 6) + (g << 4)) ^ ((row & 7) << 4);
        bf[nt] = *(const short8*)(bl + byt);
      }
      __builtin_amdgcn_s_setprio(1);
#pragma unroll
      for (int mt = 0; mt < 4; ++mt)
#pragma unroll
        for (int nt = 0; nt < 4; ++nt)
          acc[mt][nt] = mfma16(af[mt], bf[nt], acc[mt][nt]);
      __builtin_amdgcn_s_setprio(0);
    }
    __builtin_amdgcn_sched_barrier(0);
    __builtin_amdgcn_s_barrier();
  }
#undef GSTAGE

  if (MODE == 1) {
#pragma unroll
    for (int mt = 0; mt < 4; ++mt)
#pragma unroll
      for (int nt = 0; nt < 4; ++nt) {
        const int cc = tn + wn * 64 + nt * 16 + c;
        if (cc < N) {
#pragma unroll
          for (int i = 0; i < 4; ++i) {
            const size_t rr = (size_t)(tm + wm * 64 + mt * 16 + 4 * g + i);
            ((float*)Cv)[rr * N + cc] = acc[mt][nt][i];
          }
        }
      }
  } else if (tn < 768) {
    // fused RoPE: within-head col d = nt*16+c; pairs (nt, nt+2) = (d, d+32).
    const float qs = (tn + wn * 64) < 576 ? QSC : 1.0f;
    unsigned short* Cp = (unsigned short*)Cv;
#pragma unroll
    for (int mt = 0; mt < 4; ++mt)
#pragma unroll
      for (int i = 0; i < 4; ++i) {
        const int rr = tm + wm * 64 + mt * 16 + 4 * g + i;
        const int s = rr & (NS - 1);
        const float* cb = cosT + (size_t)s * NHD;
        const float* sb = sinT + (size_t)s * NHD;
#pragma unroll
        for (int p = 0; p < 2; ++p) {
          const float cn = cb[p * 16 + c];
          const float sn = sb[p * 16 + c];
          const float lo = acc[mt][p][i];
          const float hi = acc[mt][p + 2][i];
          const size_t base = (size_t)rr * QKS + tn + wn * 64 + p * 16 + c;
          Cp[base] = f2bf((lo * cn - hi * sn) * qs);
          Cp[base + 32] = f2bf((hi * cn + lo * sn) * qs);
        }
      }
  } else {
    // V columns -> V^T directly: vt[(b*3+kh)][d][s]
#pragma unroll
    for (int mt = 0; mt < 4; ++mt)
#pragma unroll
      for (int nt = 0; nt < 4; ++nt) {
        const int cc = tn + wn * 64 + nt * 16 + c;
        if (cc < 960) {
          const int rr0 = tm + wm * 64 + mt * 16 + 4 * g;
          const int bb = rr0 >> 11, ss = rr0 & (NS - 1);
          const int grp = bb * NKVH + ((cc - 768) >> 6);
          const int d = (cc - 768) & 63;
          uint32x2 pk;
          pk.x = pk2bf(acc[mt][nt][0], acc[mt][nt][1]);
          pk.y = pk2bf(acc[mt][nt][2], acc[mt][nt][3]);
          *(uint32x2*)(vtb + (size_t)grp * (NHD * NS) + (size_t)d * NS + ss) = pk;
        }
      }
  }
}

// ---------------- causal GQA flash attention ----------------
// grid = (36 bh, 32 qt-slots), qt = 31 - y (LPT). 4 waves x 16 q-rows.
// R14 structure, but PV uses mfma_16x16x16: the QK^T C-layout puts P[kv][q]
// exactly in the K=16 B-operand lanes (k = 4*(lane>>4)+e), so P feeds PV
// directly from registers — no LDS round-trip, no cross-lane ops. p_s gone
// -> LDS 32KB -> 5 blocks/CU.
__global__ __launch_bounds__(256)
void k_attn(const unsigned short* __restrict__ qkv,
            const unsigned short* __restrict__ vt,
            unsigned short* __restrict__ ao) {
  __shared__ unsigned short kv_s[2][2][4096];   // [buf][K=0/V=1][64 x 64] = 32 KB
  const int tid = threadIdx.x;
  const int w = tid >> 6, l = tid & 63, g = l >> 4, c = l & 15;
  const int bh = blockIdx.x;
  const int qt = 31 - (int)blockIdx.y;
  const int b = bh / NHEADS, h = bh - b * NHEADS, kh = h / NGRP;

  const int lr = l >> 3;
  const int swz = ((l & 7) ^ lr) << 4;
  const int r0 = 16 * w + lr;
  const int cs = (c & 7) << 4;

  // incremental staging pointers (advance by constants per tile)
  const char* kp0 = (const char*)(qkv + (size_t)b * NS * QKS + NHEADS * NHD + kh * NHD) +
                    (size_t)r0 * (QKS * 2) + swz;
  const char* kp1 = kp0 + 8 * (QKS * 2);
  const char* vp0 = (const char*)(vt + (size_t)(b * NKVH + kh) * NHD * NS) +
                    (size_t)r0 * (NS * 2) + swz;
  const char* vp1 = vp0 + 8 * (NS * 2);

  const size_t qrow = (size_t)(b * NS + qt * 64 + w * 16 + c) * QKS + h * NHD;
  const short8 qf0 = *(const short8*)(qkv + qrow + g * 8);
  const short8 qf1 = *(const short8*)(qkv + qrow + 32 + g * 8);

  const s16x4 ones4 = {0x3F80, 0x3F80, 0x3F80, 0x3F80};

  f32x4 ot[4] = {};
  f32x4 lacc = {};
  float m = -1e30f;
  const int q_g = qt * 64 + w * 16 + c;

#define STAGE(BUF)                                                \
  {                                                               \
    gload16(kp0, kv_s[BUF][0] + 16 * w * 64);                     \
    gload16(kp1, kv_s[BUF][0] + (16 * w + 8) * 64);               \
    gload16(vp0, kv_s[BUF][1] + 16 * w * 64);                     \
    gload16(vp1, kv_s[BUF][1] + (16 * w + 8) * 64);               \
    kp0 += 64 * (QKS * 2); kp1 += 64 * (QKS * 2);                 \
    vp0 += 128; vp1 += 128;                                       \
  }

#define COMPUTE(BUF, jj)                                                        \
  {                                                                             \
    const char* kl = (const char*)kv_s[BUF][0];                                 \
    const char* vl = (const char*)kv_s[BUF][1];                                 \
    f32x4 st[4] = {};                                                           \
    _Pragma("unroll")                                                           \
    for (int dc = 0; dc < 2; ++dc) {                                            \
      const int col = (dc * 64 + g * 16) ^ cs;                                  \
      const short8 qf = dc ? qf1 : qf0;                                         \
      _Pragma("unroll")                                                         \
      for (int nt = 0; nt < 4; ++nt) {                                          \
        short8 kf = *(const short8*)(kl + (nt * 16 + c) * 128 + col);           \
        st[nt] = mfma16(kf, qf, st[nt]);                                        \
      }                                                                         \
    }                                                                           \
    s16x4 vq[16];  /* A-frag of 16x16x16: V^T[nt*16+c][kb*16+4g+e] */           \
    _Pragma("unroll")                                                           \
    for (int nt = 0; nt < 4; ++nt)                                              \
      _Pragma("unroll")                                                         \
      for (int kb = 0; kb < 4; ++kb)                                            \
        vq[nt * 4 + kb] = *(const s16x4*)(vl + (nt * 16 + c) * 128 +            \
                                          ((kb * 32 + g * 8) ^ cs));            \
    if ((jj) == qt) {                                                           \
      _Pragma("unroll")                                                         \
      for (int nt = 0; nt < 4; ++nt)                                            \
        _Pragma("unroll")                                                       \
        for (int i = 0; i < 4; ++i) {                                           \
          const int kvg = (jj) * 64 + nt * 16 + 4 * g + i;                      \
          if (kvg > q_g) st[nt][i] = -1e30f;                                    \
        }                                                                       \
    }                                                                           \
    float m0 = fmaxf(fmaxf(st[0][0], st[0][1]), st[0][2]);                      \
    float m1 = fmaxf(fmaxf(st[0][3], st[1][0]), st[1][1]);                      \
    float m2 = fmaxf(fmaxf(st[1][2], st[1][3]), st[2][0]);                      \
    float m3 = fmaxf(fmaxf(st[2][1], st[2][2]), st[2][3]);                      \
    float m4 = fmaxf(fmaxf(st[3][0], st[3][1]), st[3][2]);                      \
    float inmax = fmaxf(fmaxf(fmaxf(m0, m1), fmaxf(m2, m3)),                    \
                        fmaxf(m4, st[3][3]));                                   \
    if (!__all(inmax <= m + 8.0f)) {                                            \
      float pm = fmaxf(inmax, __shfl_xor(inmax, 16));                           \
      pm = fmaxf(pm, __shfl_xor(pm, 32));                                       \
      const float mn = fmaxf(m, pm);                                            \
      const float scl = fexp2(m - mn);                                          \
      m = mn;                                                                   \
      lacc *= scl;                                                              \
      _Pragma("unroll")                                                         \
      for (int nt = 0; nt < 4; ++nt) ot[nt] *= scl;                             \
    }                                                                           \
    {                                                                           \
      union PBu { unsigned u[2]; s16x4 v; };                                    \
      PBu pb0, pb1, pb2, pb3;                                                   \
      pb0.u[0] = pk2bf(fexp2(st[0][0] - m), fexp2(st[0][1] - m));               \
      pb0.u[1] = pk2bf(fexp2(st[0][2] - m), fexp2(st[0][3] - m));               \
      pb1.u[0] = pk2bf(fexp2(st[1][0] - m), fexp2(st[1][1] - m));               \
      pb1.u[1] = pk2bf(fexp2(st[1][2] - m), fexp2(st[1][3] - m));               \
      pb2.u[0] = pk2bf(fexp2(st[2][0] - m), fexp2(st[2][1] - m));               \
      pb2.u[1] = pk2bf(fexp2(st[2][2] - m), fexp2(st[2][3] - m));               \
      pb3.u[0] = pk2bf(fexp2(st[3][0] - m), fexp2(st[3][1] - m));               \
      pb3.u[1] = pk2bf(fexp2(st[3][2] - m), fexp2(st[3][3] - m));               \
      lacc = mfma16k16(ones4, pb0.v, lacc);                                     \
      lacc = mfma16k16(ones4, pb1.v, lacc);                                     \
      lacc = mfma16k16(ones4, pb2.v, lacc);                                     \
      lacc = mfma16k16(ones4, pb3.v, lacc);                                     \
      _Pragma("unroll")                                                         \
      for (int nt = 0; nt < 4; ++nt) {                                          \
        ot[nt] = mfma16k16(vq[nt * 4 + 0], pb0.v, ot[nt]);                      \
        ot[nt] = mfma16k16(vq[nt * 4 + 1], pb1.v, ot[nt]);                      \
        ot[nt] = mfma16k16(vq[nt * 4 + 2], pb2.v, ot[nt]);                      \
        ot[nt] = mfma16k16(vq[nt * 4 + 3], pb3.v, ot[nt]);                      \
      }                                                                         \
    }                                                                           \
  }

  STAGE(0);   // tile 0 -> buf0

  for (int j = 0; j <= qt; j += 2) {
    if (j < qt) {
      STAGE(1);
      asm volatile("s_waitcnt vmcnt(4)" ::: "memory");
    } else {
      asm volatile("s_waitcnt vmcnt(0)" ::: "memory");
    }
    __builtin_amdgcn_s_barrier();
    __builtin_amdgcn_sched_barrier(0);
    COMPUTE(0, j);
    __builtin_amdgcn_sched_barrier(0);
    __builtin_amdgcn_s_barrier();
    if (j + 1 > qt) break;
    if (j + 1 < qt) {
      STAGE(0);
      asm volatile("s_waitcnt vmcnt(4)" ::: "memory");
    } else {
      asm volatile("s_waitcnt vmcnt(0)" ::: "memory");
    }
    __builtin_amdgcn_s_barrier();
    __builtin_amdgcn_sched_barrier(0);
    COMPUTE(1, j + 1);
    __builtin_amdgcn_sched_barrier(0);
    __builtin_amdgcn_s_barrier();
  }
#undef STAGE
#undef COMPUTE

  // O^T -> LDS (swizzled) -> coalesced global write
  {
    char* ol = (char*)kv_s[0][0];
    const float inv = __builtin_amdgcn_rcpf(lacc[0]);
#pragma unroll
    for (int nt = 0; nt < 4; ++nt) {
      uint32x2 pk;
      pk.x = pk2bf(ot[nt][0] * inv, ot[nt][1] * inv);
      pk.y = pk2bf(ot[nt][2] * inv, ot[nt][3] * inv);
      *(uint32x2*)(ol + (w * 16 + c) * 128 + ((nt * 32 + g * 8) ^ cs)) = pk;
    }
  }
  __syncthreads();
  {
    const char* ol = (const char*)kv_s[0][0];
    const int rr = tid >> 2, cb = tid & 3;
    const int rk = (rr & 7) << 4;
    short8 v0 = *(const short8*)(ol + rr * 128 + ((cb * 32) ^ rk));
    short8 v1 = *(const short8*)(ol + rr * 128 + ((cb * 32 + 16) ^ rk));
    char* aop = (char*)(ao + (size_t)(b * NS + qt * 64 + rr) * NHID + h * NHD + cb * 16);
    *(short8*)aop = v0;
    *(short8*)(aop + 16) = v1;
  }
}

extern "C" void kernel_launch(void* const* d_in, const int* in_sizes, int n_in,
                              void* d_out, int out_size, void* d_ws, size_t ws_size,
                              hipStream_t stream) {
  const float* x = (const float*)d_in[0];
  const float* cosT = (const float*)d_in[1];
  const float* sinT = (const float*)d_in[2];
  const float* Wq = (const float*)d_in[4];
  const float* Wk = (const float*)d_in[5];
  const float* Wv = (const float*)d_in[6];
  const float* Wo = (const float*)d_in[7];

  unsigned short* xb = (unsigned short*)d_ws;                      // [8192][576] (reused as ao)
  unsigned short* wqkvT = xb + (size_t)NM * NHID;                  // [960][576]
  unsigned short* woT = wqkvT + (size_t)NQKV * NHID;               // [576][576]
  unsigned short* qkv = woT + (size_t)NHID * NHID;                 // [8192][768] (q+k)
  unsigned short* vt = qkv + (size_t)NM * QKS;                     // [12][64][2048]
  unsigned short* ao = xb;                                         // alias (xb dead after gemm0)

  k_prep<<<dim3(2304 + 216), 256, 0, stream>>>(x, xb, Wq, Wk, Wv, Wo, wqkvT, woT);
  // QKV projection: fused RoPE (q,k -> qkv) + direct V^T (v -> vt)
  k_gemm_bt<0><<<dim3((NQKV + 127) / 128, NM / 128), 256, 0, stream>>>(
      xb, wqkvT, (void*)qkv, vt, cosT, sinT, NM, NQKV, NHID);
  k_attn<<<dim3(NB * NHEADS, NS / 64), 256, 0, stream>>>(qkv, vt, ao);
  k_gemm_bt<1><<<dim3((NHID + 127) / 128, NM / 128), 256, 0, stream>>>(
      ao, woT, d_out, nullptr, nullptr, nullptr, NM, NHID, NHID);
}

// Round 19
// 85.925 us; speedup vs baseline: 1.0392x; 1.0392x over previous
//
#include <hip/hip_runtime.h>
#include <math.h>

typedef __attribute__((ext_vector_type(4))) float f32x4;
typedef __attribute__((ext_vector_type(8))) short short8;
typedef __attribute__((ext_vector_type(8))) __bf16 bf16x8;
typedef __attribute__((ext_vector_type(2))) __bf16 bf16x2;
typedef __attribute__((ext_vector_type(2))) unsigned uint32x2;

#define NB 4
#define NS 2048
#define NHID 576
#define NHEADS 9
#define NKVH 3
#define NHD 64
#define NM (NB * NS)      // 8192 rows
#define NQKV 960          // logical qkv cols
#define QKS 768           // stored qkv row stride (q+k only; v goes to vt)
#define NGRP 3            // NHEADS / NKVH
#define QSC 0.18033688f   // (1/sqrt(64)) * log2(e)

static __device__ __forceinline__ unsigned short f2bf(float f) {
  union { float f; unsigned u; } v; v.f = f;
  unsigned r = v.u + 0x7FFFu + ((v.u >> 16) & 1u);
  return (unsigned short)(r >> 16);
}
static __device__ __forceinline__ unsigned pk2bf(float a, float b) {
  bf16x2 h;
  h.x = (__bf16)a;
  h.y = (__bf16)b;
  return __builtin_bit_cast(unsigned, h);
}
static __device__ __forceinline__ float bf2f(unsigned short h) {
  union { unsigned u; float f; } v; v.u = ((unsigned)h) << 16;
  return v.f;
}
static __device__ __forceinline__ float fexp2(float x) {
  return __builtin_amdgcn_exp2f(x);   // bare v_exp_f32 (no OCML range handling)
}
static __device__ __forceinline__ f32x4 mfma16(short8 a, short8 b, f32x4 c) {
  return __builtin_amdgcn_mfma_f32_16x16x32_bf16(
      __builtin_bit_cast(bf16x8, a), __builtin_bit_cast(bf16x8, b), c, 0, 0, 0);
}
static __device__ __forceinline__ void gload16(const void* g, void* l) {
  __builtin_amdgcn_global_load_lds(
      (const __attribute__((address_space(1))) void*)g,
      (__attribute__((address_space(3))) void*)l, 16, 0, 0);
}

// ---------------- fused prep: x f32->bf16 (blocks 0..2303) + 4 weight transposes ----------------
__global__ __launch_bounds__(256)
void k_prep(const float* __restrict__ x, unsigned short* __restrict__ xb,
            const float* __restrict__ Wq, const float* __restrict__ Wk,
            const float* __restrict__ Wv, const float* __restrict__ Wo,
            unsigned short* __restrict__ wqkvT, unsigned short* __restrict__ woT) {
  __shared__ unsigned short tile[64 * 72];
  int bid = blockIdx.x;
  if (bid < 2304) {
    const int t = bid * 256 + threadIdx.x;   // t < NM*NHID/8 exactly
    const f32x4* sp = (const f32x4*)(x + (size_t)t * 8);
    f32x4 a = sp[0], b = sp[1];
    union { short8 v; unsigned short u[8]; } o;
#pragma unroll
    for (int e = 0; e < 4; ++e) { o.u[e] = f2bf(a[e]); o.u[4 + e] = f2bf(b[e]); }
    *(short8*)(xb + (size_t)t * 8) = o.v;
    return;
  }
  bid -= 2304;
  const float* src;
  unsigned short* dst;
  int C, bx, by;
  if (bid < 81) { src = Wq; dst = wqkvT; C = 576; bx = bid % 9; by = bid / 9; }
  else if (bid < 108) { int b2 = bid - 81; src = Wk; dst = wqkvT + 576 * 576; C = 192; bx = b2 % 3; by = b2 / 3; }
  else if (bid < 135) { int b2 = bid - 108; src = Wv; dst = wqkvT + 768 * 576; C = 192; bx = b2 % 3; by = b2 / 3; }
  else { int b2 = bid - 135; src = Wo; dst = woT; C = 576; bx = b2 % 9; by = b2 / 9; }
  const int R = 576;
  const int t = threadIdx.x;
  const int r0 = by * 64, c0 = bx * 64;
  {
    const int rl = t >> 2, cb = (t & 3) * 16;
    const float* sp = src + (size_t)(r0 + rl) * C + c0 + cb;
#pragma unroll
    for (int jj = 0; jj < 4; ++jj) {
      f32x4 v = *(const f32x4*)(sp + jj * 4);
#pragma unroll
      for (int e = 0; e < 4; ++e) tile[rl * 72 + cb + jj * 4 + e] = f2bf(v[e]);
    }
  }
  __syncthreads();
  {
    const int cl = t >> 2, rb = (t & 3) * 16;
    union { short8 v; unsigned short u[8]; } o0, o1;
#pragma unroll
    for (int jj = 0; jj < 8; ++jj) {
      o0.u[jj] = tile[(rb + jj) * 72 + cl];
      o1.u[jj] = tile[(rb + 8 + jj) * 72 + cl];
    }
    unsigned short* dp = dst + (size_t)(c0 + cl) * R + r0 + rb;
    *(short8*)dp = o0.v;
    *(short8*)(dp + 8) = o1.v;
  }
}

// ---------------- GEMM: C[M][N] = A[M][K](bf16) * Bt[N][K](bf16)^T ----------------
// BM=128 BN=128 BK=64, 4 waves (2x2 of 64x64), LDS dbuf, counted-vmcnt schedule.
// MODE 0 (QKV): cols <768 -> fused RoPE (+QSC on q), write qkv (stride 768);
//               cols 768..959 (V) -> write V^T to vt[(b*3+kh)][d][s] directly.
// MODE 1: f32 out plain (O-proj).
template <int MODE>
__global__ __launch_bounds__(256)
void k_gemm_bt(const unsigned short* __restrict__ A,
               const unsigned short* __restrict__ Bt,
               void* __restrict__ Cv,
               unsigned short* __restrict__ vtb,
               const float* __restrict__ cosT,
               const float* __restrict__ sinT,
               const int M, const int N, const int K) {
  __shared__ unsigned short a_lds[2][128 * 64];
  __shared__ unsigned short b_lds[2][128 * 64];
  const int tid = threadIdx.x;
  const int w = tid >> 6, l = tid & 63, g = l >> 4, c = l & 15;
  const int tm = blockIdx.y * 128, tn = blockIdx.x * 128;
  const int wm = w >> 1, wn = w & 1;
  f32x4 acc[4][4] = {};
  const int nk = K >> 6;

#define GSTAGE(k0, half)                                                   \
  {                                                                        \
    _Pragma("unroll")                                                      \
    for (int q = 0; q < 4; ++q) {                                          \
      const int o = q * 4096 + w * 1024 + l * 16;                          \
      const int row = o >> 7;                                              \
      const int wb = (o & 127) ^ ((row & 7) << 4);                         \
      gload16(A + (size_t)(tm + row) * K + (k0) + (wb >> 1),               \
              (void*)(a_lds[half] + ((q * 4096 + w * 1024) >> 1)));        \
      gload16(Bt + (size_t)(tn + row) * K + (k0) + (wb >> 1),              \
              (void*)(b_lds[half] + ((q * 4096 + w * 1024) >> 1)));        \
    }                                                                      \
  }

  GSTAGE(0, 0);

  for (int k = 0; k < nk; ++k) {
    if (k + 1 < nk) {
      GSTAGE((k + 1) << 6, (k + 1) & 1);
      asm volatile("s_waitcnt vmcnt(8)" ::: "memory");
    } else {
      asm volatile("s_waitcnt vmcnt(0)" ::: "memory");
    }
    __builtin_amdgcn_s_barrier();
    __builtin_amdgcn_sched_barrier(0);
    const char* al = (const char*)a_lds[k & 1];
    const char* bl = (const char*)b_lds[k & 1];
#pragma unroll
    for (int dc = 0; dc < 2; ++dc) {
      short8 af[4], bf[4];
#pragma unroll
      for (int mt = 0; mt < 4; ++mt) {
        const int row = wm * 64 + mt * 16 + c;
        const int byt = ((row << 7) + (dc << 6) + (g << 4)) ^ ((row & 7) << 4);
        af[mt] = *(const short8*)(al + byt);
      }
#pragma unroll
      for (int nt = 0; nt < 4; ++nt) {
        const int row = wn * 64 + nt * 16 + c;
        const int byt = ((row << 7) + (dc << 6) + (g << 4)) ^ ((row & 7) << 4);
        bf[nt] = *(const short8*)(bl + byt);
      }
      __builtin_amdgcn_s_setprio(1);
#pragma unroll
      for (int mt = 0; mt < 4; ++mt)
#pragma unroll
        for (int nt = 0; nt < 4; ++nt)
          acc[mt][nt] = mfma16(af[mt], bf[nt], acc[mt][nt]);
      __builtin_amdgcn_s_setprio(0);
    }
    __builtin_amdgcn_sched_barrier(0);
    __builtin_amdgcn_s_barrier();
  }
#undef GSTAGE

  if (MODE == 1) {
#pragma unroll
    for (int mt = 0; mt < 4; ++mt)
#pragma unroll
      for (int nt = 0; nt < 4; ++nt) {
        const int cc = tn + wn * 64 + nt * 16 + c;
        if (cc < N) {
#pragma unroll
          for (int i = 0; i < 4; ++i) {
            const size_t rr = (size_t)(tm + wm * 64 + mt * 16 + 4 * g + i);
            ((float*)Cv)[rr * N + cc] = acc[mt][nt][i];
          }
        }
      }
  } else if (tn < 768) {
    // fused RoPE: within-head col d = nt*16+c; pairs (nt, nt+2) = (d, d+32).
    const float qs = (tn + wn * 64) < 576 ? QSC : 1.0f;
    unsigned short* Cp = (unsigned short*)Cv;
#pragma unroll
    for (int mt = 0; mt < 4; ++mt)
#pragma unroll
      for (int i = 0; i < 4; ++i) {
        const int rr = tm + wm * 64 + mt * 16 + 4 * g + i;
        const int s = rr & (NS - 1);
        const float* cb = cosT + (size_t)s * NHD;
        const float* sb = sinT + (size_t)s * NHD;
#pragma unroll
        for (int p = 0; p < 2; ++p) {
          const float cn = cb[p * 16 + c];
          const float sn = sb[p * 16 + c];
          const float lo = acc[mt][p][i];
          const float hi = acc[mt][p + 2][i];
          const size_t base = (size_t)rr * QKS + tn + wn * 64 + p * 16 + c;
          Cp[base] = f2bf((lo * cn - hi * sn) * qs);
          Cp[base + 32] = f2bf((hi * cn + lo * sn) * qs);
        }
      }
  } else {
    // V columns -> V^T directly: vt[(b*3+kh)][d][s]
#pragma unroll
    for (int mt = 0; mt < 4; ++mt)
#pragma unroll
      for (int nt = 0; nt < 4; ++nt) {
        const int cc = tn + wn * 64 + nt * 16 + c;
        if (cc < 960) {
          const int rr0 = tm + wm * 64 + mt * 16 + 4 * g;
          const int bb = rr0 >> 11, ss = rr0 & (NS - 1);
          const int grp = bb * NKVH + ((cc - 768) >> 6);
          const int d = (cc - 768) & 63;
          uint32x2 pk;
          pk.x = pk2bf(acc[mt][nt][0], acc[mt][nt][1]);
          pk.y = pk2bf(acc[mt][nt][2], acc[mt][nt][3]);
          *(uint32x2*)(vtb + (size_t)grp * (NHD * NS) + (size_t)d * NS + ss) = pk;
        }
      }
  }
}

// ---------------- causal GQA flash attention ----------------
// grid = (36 bh, 32 qt-slots), qt = 31 - y (LPT). 4 waves x 16 q-rows.
// R13 structure (counted vmcnt + dual barrier, KV dbuf, hoisted V frags,
// branch-hidden shfls) with raw v_exp_f32 (no OCML range code) for all exp.
__global__ __launch_bounds__(256)
void k_attn(const unsigned short* __restrict__ qkv,
            const unsigned short* __restrict__ vt,
            unsigned short* __restrict__ ao) {
  __shared__ unsigned short kv_s[2][2][4096];   // [buf][K=0/V=1][64 x 64] = 32 KB
  __shared__ unsigned short p_s[4][1024];       // per-wave P^T = 8 KB
  const int tid = threadIdx.x;
  const int w = tid >> 6, l = tid & 63, g = l >> 4, c = l & 15;
  const int bh = blockIdx.x;
  const int qt = 31 - (int)blockIdx.y;
  const int b = bh / NHEADS, h = bh - b * NHEADS, kh = h / NGRP;

  const int lr = l >> 3;
  const int swz = ((l & 7) ^ lr) << 4;
  const int r0 = 16 * w + lr;
  const int cs = (c & 7) << 4;

  // incremental staging pointers (advance by constants per tile)
  const char* kp0 = (const char*)(qkv + (size_t)b * NS * QKS + NHEADS * NHD + kh * NHD) +
                    (size_t)r0 * (QKS * 2) + swz;
  const char* kp1 = kp0 + 8 * (QKS * 2);
  const char* vp0 = (const char*)(vt + (size_t)(b * NKVH + kh) * NHD * NS) +
                    (size_t)r0 * (NS * 2) + swz;
  const char* vp1 = vp0 + 8 * (NS * 2);

  const size_t qrow = (size_t)(b * NS + qt * 64 + w * 16 + c) * QKS + h * NHD;
  const short8 qf0 = *(const short8*)(qkv + qrow + g * 8);
  const short8 qf1 = *(const short8*)(qkv + qrow + 32 + g * 8);

  const short8 ones = {0x3F80, 0x3F80, 0x3F80, 0x3F80, 0x3F80, 0x3F80, 0x3F80, 0x3F80};

  f32x4 ot[4] = {};
  f32x4 lacc = {};
  float m = -1e30f;
  const int q_g = qt * 64 + w * 16 + c;

#define STAGE(BUF)                                                \
  {                                                               \
    gload16(kp0, kv_s[BUF][0] + 16 * w * 64);                     \
    gload16(kp1, kv_s[BUF][0] + (16 * w + 8) * 64);               \
    gload16(vp0, kv_s[BUF][1] + 16 * w * 64);                     \
    gload16(vp1, kv_s[BUF][1] + (16 * w + 8) * 64);               \
    kp0 += 64 * (QKS * 2); kp1 += 64 * (QKS * 2);                 \
    vp0 += 128; vp1 += 128;                                       \
  }

#define COMPUTE(BUF, jj)                                                        \
  {                                                                             \
    const char* kl = (const char*)kv_s[BUF][0];                                 \
    const char* vl = (const char*)kv_s[BUF][1];                                 \
    f32x4 st[4] = {};                                                           \
    _Pragma("unroll")                                                           \
    for (int dc = 0; dc < 2; ++dc) {                                            \
      const int col = (dc * 64 + g * 16) ^ cs;                                  \
      const short8 qf = dc ? qf1 : qf0;                                         \
      _Pragma("unroll")                                                         \
      for (int nt = 0; nt < 4; ++nt) {                                          \
        short8 kf = *(const short8*)(kl + (nt * 16 + c) * 128 + col);           \
        st[nt] = mfma16(kf, qf, st[nt]);                                        \
      }                                                                         \
    }                                                                           \
    short8 vf[8];                                                               \
    _Pragma("unroll")                                                           \
    for (int dc = 0; dc < 2; ++dc) {                                            \
      const int col = (dc * 64 + g * 16) ^ cs;                                  \
      _Pragma("unroll")                                                         \
      for (int nt = 0; nt < 4; ++nt)                                            \
        vf[dc * 4 + nt] = *(const short8*)(vl + (nt * 16 + c) * 128 + col);     \
    }                                                                           \
    if ((jj) == qt) {                                                           \
      _Pragma("unroll")                                                         \
      for (int nt = 0; nt < 4; ++nt)                                            \
        _Pragma("unroll")                                                       \
        for (int i = 0; i < 4; ++i) {                                           \
          const int kvg = (jj) * 64 + nt * 16 + 4 * g + i;                      \
          if (kvg > q_g) st[nt][i] = -1e30f;                                    \
        }                                                                       \
    }                                                                           \
    float m0 = fmaxf(fmaxf(st[0][0], st[0][1]), st[0][2]);                      \
    float m1 = fmaxf(fmaxf(st[0][3], st[1][0]), st[1][1]);                      \
    float m2 = fmaxf(fmaxf(st[1][2], st[1][3]), st[2][0]);                      \
    float m3 = fmaxf(fmaxf(st[2][1], st[2][2]), st[2][3]);                      \
    float m4 = fmaxf(fmaxf(st[3][0], st[3][1]), st[3][2]);                      \
    float inmax = fmaxf(fmaxf(fmaxf(m0, m1), fmaxf(m2, m3)),                    \
                        fmaxf(m4, st[3][3]));                                   \
    if (!__all(inmax <= m + 8.0f)) {                                            \
      float pm = fmaxf(inmax, __shfl_xor(inmax, 16));                           \
      pm = fmaxf(pm, __shfl_xor(pm, 32));                                       \
      const float mn = fmaxf(m, pm);                                            \
      const float scl = fexp2(m - mn);                                          \
      m = mn;                                                                   \
      lacc *= scl;                                                              \
      _Pragma("unroll")                                                         \
      for (int nt = 0; nt < 4; ++nt) ot[nt] *= scl;                             \
    }                                                                           \
    {                                                                           \
      char* pw = (char*)p_s[w];                                                 \
      _Pragma("unroll")                                                         \
      for (int nt = 0; nt < 4; ++nt) {                                          \
        float p0 = fexp2(st[nt][0] - m);                                        \
        float p1 = fexp2(st[nt][1] - m);                                        \
        float p2 = fexp2(st[nt][2] - m);                                        \
        float p3 = fexp2(st[nt][3] - m);                                        \
        uint32x2 pk;                                                            \
        pk.x = pk2bf(p0, p1);                                                   \
        pk.y = pk2bf(p2, p3);                                                   \
        *(uint32x2*)(pw + c * 128 + ((nt * 32 + g * 8) ^ cs)) = pk;             \
      }                                                                         \
      _Pragma("unroll")                                                         \
      for (int dc = 0; dc < 2; ++dc) {                                          \
        const int col = (dc * 64 + g * 16) ^ cs;                                \
        short8 pf = *(const short8*)(pw + c * 128 + col);                       \
        lacc = mfma16(ones, pf, lacc);                                          \
        _Pragma("unroll")                                                       \
        for (int nt = 0; nt < 4; ++nt)                                          \
          ot[nt] = mfma16(vf[dc * 4 + nt], pf, ot[nt]);                         \
      }                                                                         \
    }                                                                           \
  }

  STAGE(0);   // tile 0 -> buf0

  for (int j = 0; j <= qt; j += 2) {
    if (j < qt) {
      STAGE(1);
      asm volatile("s_waitcnt vmcnt(4)" ::: "memory");
    } else {
      asm volatile("s_waitcnt vmcnt(0)" ::: "memory");
    }
    __builtin_amdgcn_s_barrier();
    __builtin_amdgcn_sched_barrier(0);
    COMPUTE(0, j);
    __builtin_amdgcn_sched_barrier(0);
    __builtin_amdgcn_s_barrier();
    if (j + 1 > qt) break;
    if (j + 1 < qt) {
      STAGE(0);
      asm volatile("s_waitcnt vmcnt(4)" ::: "memory");
    } else {
      asm volatile("s_waitcnt vmcnt(0)" ::: "memory");
    }
    __builtin_amdgcn_s_barrier();
    __builtin_amdgcn_sched_barrier(0);
    COMPUTE(1, j + 1);
    __builtin_amdgcn_sched_barrier(0);
    __builtin_amdgcn_s_barrier();
  }
#undef STAGE
#undef COMPUTE

  // O^T -> LDS (swizzled) -> coalesced global write
  {
    char* ol = (char*)kv_s[0][0];
    const float inv = __builtin_amdgcn_rcpf(lacc[0]);
#pragma unroll
    for (int nt = 0; nt < 4; ++nt) {
      uint32x2 pk;
      pk.x = pk2bf(ot[nt][0] * inv, ot[nt][1] * inv);
      pk.y = pk2bf(ot[nt][2] * inv, ot[nt][3] * inv);
      *(uint32x2*)(ol + (w * 16 + c) * 128 + ((nt * 32 + g * 8) ^ cs)) = pk;
    }
  }
  __syncthreads();
  {
    const char* ol = (const char*)kv_s[0][0];
    const int rr = tid >> 2, cb = tid & 3;
    const int rk = (rr & 7) << 4;
    short8 v0 = *(const short8*)(ol + rr * 128 + ((cb * 32) ^ rk));
    short8 v1 = *(const short8*)(ol + rr * 128 + ((cb * 32 + 16) ^ rk));
    char* aop = (char*)(ao + (size_t)(b * NS + qt * 64 + rr) * NHID + h * NHD + cb * 16);
    *(short8*)aop = v0;
    *(short8*)(aop + 16) = v1;
  }
}

extern "C" void kernel_launch(void* const* d_in, const int* in_sizes, int n_in,
                              void* d_out, int out_size, void* d_ws, size_t ws_size,
                              hipStream_t stream) {
  const float* x = (const float*)d_in[0];
  const float* cosT = (const float*)d_in[1];
  const float* sinT = (const float*)d_in[2];
  const float* Wq = (const float*)d_in[4];
  const float* Wk = (const float*)d_in[5];
  const float* Wv = (const float*)d_in[6];
  const float* Wo = (const float*)d_in[7];

  unsigned short* xb = (unsigned short*)d_ws;                      // [8192][576] (reused as ao)
  unsigned short* wqkvT = xb + (size_t)NM * NHID;                  // [960][576]
  unsigned short* woT = wqkvT + (size_t)NQKV * NHID;               // [576][576]
  unsigned short* qkv = woT + (size_t)NHID * NHID;                 // [8192][768] (q+k)
  unsigned short* vt = qkv + (size_t)NM * QKS;                     // [12][64][2048]
  unsigned short* ao = xb;                                         // alias (xb dead after gemm0)

  k_prep<<<dim3(2304 + 216), 256, 0, stream>>>(x, xb, Wq, Wk, Wv, Wo, wqkvT, woT);
  // QKV projection: fused RoPE (q,k -> qkv) + direct V^T (v -> vt)
  k_gemm_bt<0><<<dim3((NQKV + 127) / 128, NM / 128), 256, 0, stream>>>(
      xb, wqkvT, (void*)qkv, vt, cosT, sinT, NM, NQKV, NHID);
  k_attn<<<dim3(NB * NHEADS, NS / 64), 256, 0, stream>>>(qkv, vt, ao);
  k_gemm_bt<1><<<dim3((NHID + 127) / 128, NM / 128), 256, 0, stream>>>(
      ao, woT, d_out, nullptr, nullptr, nullptr, NM, NHID, NHID);
}